// Round 1
// 4271.946 us; speedup vs baseline: 1.0753x; 1.0753x over previous
//
#include <hip/hip_runtime.h>
#include <stdint.h>

// Seq2seq LSTM, f32 in/out, bf16 MFMA, fp32 cell state.
// R10:
//  Encoder: unchanged from R8/R9 (persistent, 16x16 groups, register weights,
//   agent-atomic h exchange + flag barrier, LDS staging). ~2.4ms, latency-bound.
//  Decoder: PERSISTENT single kernel (was 128 launches). 256 blocks =
//   32 row-groups(128 rows) x 8 hid-slices(32 hid), 1 block/CU.
//   Wih1+Whh1 B-frags in LDS (128KB, staged once); Whh0 streamed from L2 pk.
//   c0/c1 in registers. Per step: phase A (Whh0 GEMM + Whh1@h1(t-1) GEMM +
//   cell0, publish h0 slice), barrier(8 same-rg blocks, same XCD by swizzle),
//   phase B (Wih1@h0(t) GEMM + cell1 + pred reduce/atomicAdd, publish h1),
//   barrier. h/pred exchange via relaxed agent-scope atomics (LLC), mirroring
//   the proven encoder protocol. Ping-pong h buffers by step parity.

typedef short short8v __attribute__((ext_vector_type(8)));
typedef float float4v __attribute__((ext_vector_type(4)));
typedef unsigned long long u64;
#define MFMA(a,b,c) __builtin_amdgcn_mfma_f32_16x16x32_bf16((a),(b),(c),0,0,0)

#define HIDN 256
#define TLEN 512
#define HPE  ((size_t)256 * HIDN)     // enc h slot elements (128 KB)
#define HPD  ((size_t)4096 * HIDN)    // dec h slot elements (2 MB bf16)

__device__ __forceinline__ unsigned short f2b(float f) {
    unsigned int u = __float_as_uint(f);
    unsigned int r = ((u >> 16) & 1u) + 0x7FFFu;
    return (unsigned short)((u + r) >> 16);
}
__device__ __forceinline__ float sigf(float x) { return 1.0f / (1.0f + __expf(-x)); }
__device__ __forceinline__ float tanhf2(float x) { return 1.0f - 2.0f / (1.0f + __expf(2.0f * x)); }

__device__ __forceinline__ void hpair_store(unsigned short* buf, int row, int hid,
                                            float h, int lane) {
    unsigned int mine = f2b(h);
    unsigned int part = (unsigned int)__shfl_xor((int)mine, 1);
    if (!(lane & 1)) {
        __hip_atomic_store((unsigned int*)&buf[(size_t)row * HIDN + hid],
                           mine | (part << 16),
                           __ATOMIC_RELAXED, __HIP_MEMORY_SCOPE_AGENT);
    }
}

// agent-scope (LLC-coherent) 16B A-frag load as 2x u64
__device__ __forceinline__ short8v ldA16(const unsigned short* p) {
    union { u64 d[2]; short8v v; } w;
    w.d[0] = __hip_atomic_load((const u64*)p,     __ATOMIC_RELAXED, __HIP_MEMORY_SCOPE_AGENT);
    w.d[1] = __hip_atomic_load((const u64*)p + 1, __ATOMIC_RELAXED, __HIP_MEMORY_SCOPE_AGENT);
    return w.v;
}

__device__ __forceinline__ void bar_sync(unsigned int* fl, int slot, unsigned int target,
                                         int lane, int tid, int& dead) {
    __syncthreads();
    if (tid == 0)
        __hip_atomic_store(&fl[slot], target, __ATOMIC_RELAXED, __HIP_MEMORY_SCOPE_AGENT);
    if (!dead) {
        int guard = 0;
        for (;;) {
            unsigned int v = 0xFFFFFFFFu;
            if (lane < 16)
                v = __hip_atomic_load(&fl[lane], __ATOMIC_RELAXED, __HIP_MEMORY_SCOPE_AGENT);
            if (__ballot(v >= target) == ~0ull) break;
            if (++guard > (1 << 20)) { dead = 1; break; }
        }
    }
    __builtin_amdgcn_fence(__ATOMIC_ACQUIRE, "workgroup");
}

__device__ __forceinline__ void bar8_sync(unsigned int* fl, int slot, unsigned int target,
                                          int lane, int tid, int& dead) {
    __syncthreads();
    if (tid == 0)
        __hip_atomic_store(&fl[slot], target, __ATOMIC_RELAXED, __HIP_MEMORY_SCOPE_AGENT);
    if (!dead) {
        int guard = 0;
        for (;;) {
            unsigned int v = 0xFFFFFFFFu;
            if (lane < 8)
                v = __hip_atomic_load(&fl[lane], __ATOMIC_RELAXED, __HIP_MEMORY_SCOPE_AGENT);
            if (__ballot(v >= target) == ~0ull) break;
            if (++guard > (1 << 20)) { dead = 1; break; }
        }
    }
    __builtin_amdgcn_fence(__ATOMIC_ACQUIRE, "workgroup");
}

// ==================== DEC WEIGHT PACK (one-time) ====================
// pk slot = ((mat*64 + n)*8 + kc)*64 + lane; element W[n*16+(lane&15)][kc*32+(lane>>4)*8+i]
__global__ __launch_bounds__(256) void pack_kernel(
    const float* __restrict__ Whh0, const float* __restrict__ Wih1,
    const float* __restrict__ Whh1, unsigned short* __restrict__ pk)
{
    int gid = blockIdx.x * 256 + threadIdx.x;   // 0..98303
    int lane = gid & 63;
    int kc = (gid >> 6) & 7;
    int n  = (gid >> 9) & 63;
    int mat = gid >> 15;
    const float* W = (mat == 0) ? Whh0 : ((mat == 1) ? Wih1 : Whh1);
    const float* p = W + (size_t)(n * 16 + (lane & 15)) * HIDN
                       + (kc << 5) + ((lane >> 4) << 3);
    short8v v;
#pragma unroll
    for (int i = 0; i < 8; ++i) v[i] = (short)f2b(p[i]);
    *(short8v*)&pk[(size_t)gid << 3] = v;
}

// ============================ ENCODER (unchanged) ============================
__global__ __launch_bounds__(256, 1) void enc_kernel(
    const float* __restrict__ x,
    const float* __restrict__ Wih0, const float* __restrict__ Whh0, const float* __restrict__ b0,
    const float* __restrict__ Wih1, const float* __restrict__ Whh1, const float* __restrict__ b1,
    unsigned short* __restrict__ h0e, unsigned short* __restrict__ h1e,
    unsigned short* __restrict__ finh0, unsigned short* __restrict__ finh1,
    float* __restrict__ finc0, float* __restrict__ finc1,
    unsigned int* __restrict__ flags)
{
    const int tid = threadIdx.x, lane = tid & 63, wv = tid >> 6;
    const int bt = blockIdx.x & 15, hs = blockIdx.x >> 4;
    const int row0 = bt << 4, hidb = hs << 4;
    const int l15 = lane & 15, q = lane >> 4, q8 = q << 3;

    __shared__ float gt[12][16][17];
    __shared__ float xt[16][TLEN + 1];
    __shared__ unsigned short hst0[16][264], hst1[16][264];

    for (int idx = tid; idx < 16 * TLEN; idx += 256) {
        int r = idx >> 9, c = idx & 511;
        xt[r][c] = x[(size_t)(row0 + r) * TLEN + c];
    }

    short8v wf[3][8];
    {
        const float* Ws[3] = {Whh0, Wih1, Whh1};
#pragma unroll
        for (int j = 0; j < 3; ++j) {
            int p = wv * 3 + j;
            int mat = p >> 2, g = p & 3;
            const float* rp = Ws[mat] + (size_t)((g << 8) + hidb + l15) * HIDN + q8;
#pragma unroll
            for (int kc = 0; kc < 8; ++kc) {
                short8v v;
#pragma unroll
                for (int i = 0; i < 8; ++i) v[i] = (short)f2b(rp[(kc << 5) + i]);
                wf[j][kc] = v;
            }
        }
    }

    const int erow = tid >> 4, ehid = tid & 15;
    const int grow = row0 + erow, ghid = hidb + ehid;
    float wx[4], bb0v[4], bb1v[4];
#pragma unroll
    for (int g = 0; g < 4; ++g) {
        wx[g]   = Wih0[(g << 8) + ghid];
        bb0v[g] = b0[(g << 8) + ghid];
        bb1v[g] = b1[(g << 8) + ghid];
    }
    float c0 = 0.f, c1 = 0.f;
    unsigned int* fl = flags + (bt << 4);
    int dead = 0;
    const bool useH0 = (wv <= 2), useH1 = (wv >= 2);
    __syncthreads();

    for (int s = 1; s <= 513; ++s) {
        const unsigned short* hr0 = h0e + (size_t)((s - 1) & 1) * HPE;
        const unsigned short* hr1 = h1e + (size_t)((s - 1) & 1) * HPE;
        unsigned short* hw0 = h0e + (size_t)(s & 1) * HPE;
        unsigned short* hw1 = h1e + (size_t)(s & 1) * HPE;

        if (s >= 2) {
#pragma unroll
            for (int k = 0; k < 4; ++k) {
                int oo = tid + (k << 8);
                int r = oo >> 6, cu = oo & 63;
                u64 v = __hip_atomic_load((const u64*)&hr0[(size_t)(row0 + r) * HIDN + (cu << 2)],
                                          __ATOMIC_RELAXED, __HIP_MEMORY_SCOPE_AGENT);
                *(u64*)&hst0[r][cu << 2] = v;
            }
        }
        if (s >= 3) {
#pragma unroll
            for (int k = 0; k < 4; ++k) {
                int oo = tid + (k << 8);
                int r = oo >> 6, cu = oo & 63;
                u64 v = __hip_atomic_load((const u64*)&hr1[(size_t)(row0 + r) * HIDN + (cu << 2)],
                                          __ATOMIC_RELAXED, __HIP_MEMORY_SCOPE_AGENT);
                *(u64*)&hst1[r][cu << 2] = v;
            }
        }
        __syncthreads();

        float4v acc[3] = {{0,0,0,0},{0,0,0,0},{0,0,0,0}};
        short8v a0f[8], a1f[8];
        if (useH0 && s >= 2) {
#pragma unroll
            for (int kc = 0; kc < 8; ++kc) a0f[kc] = *(const short8v*)&hst0[l15][(kc << 5) + q8];
        }
        if (useH1 && s >= 3) {
#pragma unroll
            for (int kc = 0; kc < 8; ++kc) a1f[kc] = *(const short8v*)&hst1[l15][(kc << 5) + q8];
        }
#pragma unroll
        for (int j = 0; j < 3; ++j) {
            int p = wv * 3 + j;
            int mat = p >> 2;
            bool active = (mat == 0) ? (s >= 2 && s <= 512)
                        : (mat == 1) ? (s >= 2)
                                     : (s >= 3);
            if (active) {
                if (mat == 2) {
#pragma unroll
                    for (int kc = 0; kc < 8; ++kc) acc[j] = MFMA(a1f[kc], wf[j][kc], acc[j]);
                } else {
#pragma unroll
                    for (int kc = 0; kc < 8; ++kc) acc[j] = MFMA(a0f[kc], wf[j][kc], acc[j]);
                }
            }
        }
#pragma unroll
        for (int j = 0; j < 3; ++j) {
            int p = wv * 3 + j;
#pragma unroll
            for (int r = 0; r < 4; ++r) gt[p][(q << 2) + r][l15] = acc[j][r];
        }
        __syncthreads();

        if (s <= 512) {
            float xv = xt[erow][s - 1];
            float gi = gt[0][erow][ehid] + wx[0] * xv + bb0v[0];
            float gf = gt[1][erow][ehid] + wx[1] * xv + bb0v[1];
            float gg = gt[2][erow][ehid] + wx[2] * xv + bb0v[2];
            float go = gt[3][erow][ehid] + wx[3] * xv + bb0v[3];
            c0 = sigf(gf) * c0 + sigf(gi) * tanhf2(gg);
            float h0n = sigf(go) * tanhf2(c0);
            hpair_store(hw0, grow, ghid, h0n, lane);
            if (s == 512) {
                finh0[(size_t)grow * HIDN + ghid] = f2b(h0n);
                finc0[(size_t)grow * HIDN + ghid] = c0;
            }
        }
        if (s >= 2) {
            float gi = gt[4][erow][ehid] + gt[8][erow][ehid]  + bb1v[0];
            float gf = gt[5][erow][ehid] + gt[9][erow][ehid]  + bb1v[1];
            float gg = gt[6][erow][ehid] + gt[10][erow][ehid] + bb1v[2];
            float go = gt[7][erow][ehid] + gt[11][erow][ehid] + bb1v[3];
            c1 = sigf(gf) * c1 + sigf(gi) * tanhf2(gg);
            float h1n = sigf(go) * tanhf2(c1);
            hpair_store(hw1, grow, ghid, h1n, lane);
            if (s == 513) {
                finh1[(size_t)grow * HIDN + ghid] = f2b(h1n);
                finc1[(size_t)grow * HIDN + ghid] = c1;
            }
        }
        bar_sync(fl, hs, (unsigned int)s, lane, tid, dead);
    }
}

// ===================== PERSISTENT DECODER =====================
// 256 blocks = 32 row-groups(128 rows) x 8 hid-slices(32 hid), 1 block/CU.
// blockIdx: rg = bid & 31, hsl = bid >> 5 -> same-rg siblings share XCD
// (round-robin dispatch heuristic; correctness from agent-scope atomics).
__global__ __launch_bounds__(256, 1) void dec_kernel(
    const unsigned short* __restrict__ pk,
    const float* __restrict__ Wih0, const float* __restrict__ b0,
    const float* __restrict__ b1, const float* __restrict__ outW,
    const float* __restrict__ outb, const float* __restrict__ dinit,
    const unsigned short* __restrict__ finh0, const float* __restrict__ finc0,
    const unsigned short* __restrict__ finh1, const float* __restrict__ finc1,
    unsigned short* __restrict__ h0d, unsigned short* __restrict__ h1d,
    float* __restrict__ predbuf, unsigned int* __restrict__ flags,
    float* __restrict__ out)
{
    extern __shared__ unsigned short wlds[];   // 128KB: [mt(2)][nf(8)][kc(8)][ln(64)] x16B
    const int tid = threadIdx.x, lane = tid & 63, wv = tid >> 6;
    const int rg = blockIdx.x & 31, hsl = blockIdx.x >> 5;
    const int row0 = rg << 7, hidb = hsl << 5;
    const int l15 = lane & 15, q = lane >> 4, q8 = q << 3;

    // stage Wih1 (mt=0) + Whh1 (mt=1) B-frags into LDS, once
#pragma unroll
    for (int k = 0; k < 32; ++k) {
        int sl = tid + (k << 8);
        int ln = sl & 63, kc = (sl >> 6) & 7, nf = (sl >> 9) & 7, mt = sl >> 12;
        int n = ((mt + 1) << 6) + ((nf >> 1) << 4) + (hsl << 1) + (nf & 1);
        *(short8v*)&wlds[sl << 3] =
            *(const short8v*)&pk[((size_t)((n << 3) + kc) << 9) + (ln << 3)];
    }

    const float outb_v = outb[0];
    float wx2[2][4], bb0v[2][4], bb1v[2][4], ow2[2];
#pragma unroll
    for (int u = 0; u < 2; ++u) {
        int hid = hidb + (u << 4) + l15;
        ow2[u] = outW[hid];
#pragma unroll
        for (int g = 0; g < 4; ++g) {
            wx2[u][g]  = Wih0[(g << 8) + hid];
            bb0v[u][g] = b0[(g << 8) + hid];
            bb1v[u][g] = b1[(g << 8) + hid];
        }
    }
    // cell state in registers
    float c0r[2][2][4], c1r[2][2][4];
#pragma unroll
    for (int m = 0; m < 2; ++m)
#pragma unroll
        for (int u = 0; u < 2; ++u) {
            int hid = hidb + (u << 4) + l15;
#pragma unroll
            for (int r = 0; r < 4; ++r) {
                int row = row0 + (wv << 5) + (m << 4) + (q << 2) + r;
                c0r[m][u][r] = finc0[(size_t)(row & 255) * HIDN + hid];
                c1r[m][u][r] = finc1[(size_t)(row & 255) * HIDN + hid];
            }
        }
    unsigned int* fl = flags + (rg << 4);
    int dead = 0;
    __syncthreads();

    for (int t = 0; t < 64; ++t) {
        const unsigned short* h0prev = (t == 0) ? finh0 : h0d + (size_t)((t + 1) & 1) * HPD;
        const unsigned short* h1prev = (t == 0) ? finh1 : h1d + (size_t)((t + 1) & 1) * HPD;
        unsigned short* h0w = h0d + (size_t)(t & 1) * HPD;
        unsigned short* h1w = h1d + (size_t)(t & 1) * HPD;
        const int rmask = (t == 0) ? 255 : 0x7FFFFFFF;

        // ---- phase A: A-frags h0(t-1), h1(t-1) (agent/LLC) ----
        short8v af0[2][8], af1[2][8];
#pragma unroll
        for (int m = 0; m < 2; ++m) {
            int row = (row0 + (wv << 5) + (m << 4) + l15) & rmask;
            const unsigned short* p0 = h0prev + (size_t)row * HIDN + q8;
            const unsigned short* p1 = h1prev + (size_t)row * HIDN + q8;
#pragma unroll
            for (int kc = 0; kc < 8; ++kc) {
                af0[m][kc] = ldA16(p0 + (kc << 5));
                af1[m][kc] = ldA16(p1 + (kc << 5));
            }
        }
        // input scalar (pred(t-1)+outb or dec_init)
        float inp[2][4];
#pragma unroll
        for (int m = 0; m < 2; ++m)
#pragma unroll
            for (int r = 0; r < 4; ++r) {
                int row = row0 + (wv << 5) + (m << 4) + (q << 2) + r;
                inp[m][r] = (t == 0) ? dinit[row]
                    : __hip_atomic_load(&predbuf[(size_t)(t - 1) * 4096 + row],
                                        __ATOMIC_RELAXED, __HIP_MEMORY_SCOPE_AGENT) + outb_v;
            }
        // write out[t-1] (pred(t-1) synced by previous barrier)
        if (hsl == 0 && t > 0 && tid < 128) {
            int row = row0 + tid;
            float v = __hip_atomic_load(&predbuf[(size_t)(t - 1) * 4096 + row],
                                        __ATOMIC_RELAXED, __HIP_MEMORY_SCOPE_AGENT) + outb_v;
            out[(size_t)(((row & 255) << 4) + (row >> 8)) * 64 + (t - 1)] = v;
        }

        // acc0 = h0(t-1) @ Whh0 (B-frags streamed from L2-resident pk)
        float4v acc0[2][8];
#pragma unroll
        for (int m = 0; m < 2; ++m)
#pragma unroll
            for (int nf = 0; nf < 8; ++nf) acc0[m][nf] = (float4v){0, 0, 0, 0};
#pragma unroll
        for (int kc = 0; kc < 8; ++kc)
#pragma unroll
            for (int nf = 0; nf < 8; ++nf) {
                int n = ((nf >> 1) << 4) + (hsl << 1) + (nf & 1);
                short8v bf = *(const short8v*)&pk[((size_t)((n << 3) + kc) << 9) + (lane << 3)];
                acc0[0][nf] = MFMA(af0[0][kc], bf, acc0[0][nf]);
                acc0[1][nf] = MFMA(af0[1][kc], bf, acc0[1][nf]);
            }
        // acc1 partial = h1(t-1) @ Whh1 (LDS mt=1)
        float4v acc1[2][8];
#pragma unroll
        for (int m = 0; m < 2; ++m)
#pragma unroll
            for (int nf = 0; nf < 8; ++nf) acc1[m][nf] = (float4v){0, 0, 0, 0};
#pragma unroll
        for (int kc = 0; kc < 8; ++kc)
#pragma unroll
            for (int nf = 0; nf < 8; ++nf) {
                short8v bf = *(const short8v*)&wlds[(size_t)((((8 + nf) << 3) + kc) << 6 | lane) << 3];
                acc1[0][nf] = MFMA(af1[0][kc], bf, acc1[0][nf]);
                acc1[1][nf] = MFMA(af1[1][kc], bf, acc1[1][nf]);
            }
        // cell0 -> publish h0(t) slice
#pragma unroll
        for (int m = 0; m < 2; ++m)
#pragma unroll
            for (int u = 0; u < 2; ++u) {
                int hid = hidb + (u << 4) + l15;
#pragma unroll
                for (int r = 0; r < 4; ++r) {
                    int row = row0 + (wv << 5) + (m << 4) + (q << 2) + r;
                    float gi = acc0[m][0 + u][r] + wx2[u][0] * inp[m][r] + bb0v[u][0];
                    float gf = acc0[m][2 + u][r] + wx2[u][1] * inp[m][r] + bb0v[u][1];
                    float gg = acc0[m][4 + u][r] + wx2[u][2] * inp[m][r] + bb0v[u][2];
                    float go = acc0[m][6 + u][r] + wx2[u][3] * inp[m][r] + bb0v[u][3];
                    float cn = sigf(gf) * c0r[m][u][r] + sigf(gi) * tanhf2(gg);
                    c0r[m][u][r] = cn;
                    float h0n = sigf(go) * tanhf2(cn);
                    hpair_store(h0w, row, hid, h0n, lane);
                }
            }
        bar8_sync(fl, hsl, (unsigned int)(2 * t + 1), lane, tid, dead);

        // ---- phase B: acc1 += h0(t) @ Wih1 (LDS mt=0) ----
        short8v af0n[2][8];
#pragma unroll
        for (int m = 0; m < 2; ++m) {
            int row = row0 + (wv << 5) + (m << 4) + l15;
            const unsigned short* p0 = h0w + (size_t)row * HIDN + q8;
#pragma unroll
            for (int kc = 0; kc < 8; ++kc) af0n[m][kc] = ldA16(p0 + (kc << 5));
        }
#pragma unroll
        for (int kc = 0; kc < 8; ++kc)
#pragma unroll
            for (int nf = 0; nf < 8; ++nf) {
                short8v bf = *(const short8v*)&wlds[(size_t)(((nf << 3) + kc) << 6 | lane) << 3];
                acc1[0][nf] = MFMA(af0n[0][kc], bf, acc1[0][nf]);
                acc1[1][nf] = MFMA(af0n[1][kc], bf, acc1[1][nf]);
            }
        // cell1 -> publish h1(t) slice + pred partial
        float pp[2][4] = {{0,0,0,0},{0,0,0,0}};
#pragma unroll
        for (int m = 0; m < 2; ++m)
#pragma unroll
            for (int u = 0; u < 2; ++u) {
                int hid = hidb + (u << 4) + l15;
#pragma unroll
                for (int r = 0; r < 4; ++r) {
                    int row = row0 + (wv << 5) + (m << 4) + (q << 2) + r;
                    float gi = acc1[m][0 + u][r] + bb1v[u][0];
                    float gf = acc1[m][2 + u][r] + bb1v[u][1];
                    float gg = acc1[m][4 + u][r] + bb1v[u][2];
                    float go = acc1[m][6 + u][r] + bb1v[u][3];
                    float cn = sigf(gf) * c1r[m][u][r] + sigf(gi) * tanhf2(gg);
                    c1r[m][u][r] = cn;
                    float h1n = sigf(go) * tanhf2(cn);
                    pp[m][r] += h1n * ow2[u];
                    hpair_store(h1w, row, hid, h1n, lane);
                }
            }
#pragma unroll
        for (int off = 1; off < 16; off <<= 1)
#pragma unroll
            for (int m = 0; m < 2; ++m)
#pragma unroll
                for (int r = 0; r < 4; ++r) pp[m][r] += __shfl_xor(pp[m][r], off);
        if (l15 == 0) {
#pragma unroll
            for (int m = 0; m < 2; ++m)
#pragma unroll
                for (int r = 0; r < 4; ++r) {
                    int row = row0 + (wv << 5) + (m << 4) + (q << 2) + r;
                    atomicAdd(&predbuf[(size_t)t * 4096 + row], pp[m][r]);
                }
        }
        bar8_sync(fl, hsl, (unsigned int)(2 * t + 2), lane, tid, dead);
    }

    // final output column t=63
    if (hsl == 0 && tid < 128) {
        int row = row0 + tid;
        float v = __hip_atomic_load(&predbuf[(size_t)63 * 4096 + row],
                                    __ATOMIC_RELAXED, __HIP_MEMORY_SCOPE_AGENT) + outb_v;
        out[(size_t)(((row & 255) << 4) + (row >> 8)) * 64 + 63] = v;
    }
}

extern "C" void kernel_launch(void* const* d_in, const int* in_sizes, int n_in,
                              void* d_out, int out_size, void* d_ws, size_t ws_size,
                              hipStream_t stream) {
    (void)in_sizes; (void)n_in; (void)out_size; (void)ws_size;
    const float* x     = (const float*)d_in[0];
    const float* eWih0 = (const float*)d_in[1];
    const float* eWhh0 = (const float*)d_in[2];
    const float* eb0   = (const float*)d_in[3];
    const float* eWih1 = (const float*)d_in[4];
    const float* eWhh1 = (const float*)d_in[5];
    const float* eb1   = (const float*)d_in[6];
    const float* dWih0 = (const float*)d_in[7];
    const float* dWhh0 = (const float*)d_in[8];
    const float* db0   = (const float*)d_in[9];
    const float* dWih1 = (const float*)d_in[10];
    const float* dWhh1 = (const float*)d_in[11];
    const float* db1   = (const float*)d_in[12];
    const float* outW  = (const float*)d_in[13];
    const float* outb  = (const float*)d_in[14];
    const float* dinit = (const float*)d_in[15];

    char* ws = (char*)d_ws;
    unsigned short* h0e   = (unsigned short*)(ws);               // 256 KB
    unsigned short* h1e   = (unsigned short*)(ws + 262144);      // 256 KB
    unsigned short* finh0 = (unsigned short*)(ws + 524288);      // 128 KB
    unsigned short* finh1 = (unsigned short*)(ws + 655360);      // 128 KB
    float* finc0          = (float*)(ws + 786432);               // 256 KB
    float* finc1          = (float*)(ws + 1048576);              // 256 KB
    unsigned int* fle     = (unsigned int*)(ws + 1310720);       // 1 KB
    unsigned short* pk    = (unsigned short*)(ws + 1311744);     // 1.5 MB
    unsigned short* h0d   = (unsigned short*)(ws + 2884608);     // 2x2 MB
    unsigned short* h1d   = (unsigned short*)(ws + 7078912);     // 2x2 MB
    unsigned int* fld     = (unsigned int*)(ws + 11273216);      // 2 KB (32 rg x 16)
    float* predraw        = (float*)(ws + 19661824);             // 1 MB (64 x 4096)

    hipMemsetAsync(fle, 0, 1024, stream);
    hipMemsetAsync(fld, 0, 2048, stream);
    hipMemsetAsync(predraw, 0, 64 * 4096 * 4, stream);
    hipFuncSetAttribute((const void*)dec_kernel,
                        hipFuncAttributeMaxDynamicSharedMemorySize, 131072);

    pack_kernel<<<384, 256, 0, stream>>>(dWhh0, dWih1, dWhh1, pk);
    enc_kernel<<<256, 256, 0, stream>>>(x, eWih0, eWhh0, eb0, eWih1, eWhh1, eb1,
                                        h0e, h1e, finh0, finh1, finc0, finc1, fle);
    dec_kernel<<<256, 256, 131072, stream>>>(pk, dWih0, db0, db1, outW, outb, dinit,
                                             finh0, finc0, finh1, finc1,
                                             h0d, h1d, predraw, fld, (float*)d_out);
}

// Round 2
// 4142.743 us; speedup vs baseline: 1.1088x; 1.0312x over previous
//
#include <hip/hip_runtime.h>
#include <stdint.h>

// Seq2seq LSTM, f32 in/out, bf16 MFMA, fp32 cell state.
// R11:
//  Encoder: R8 structure; barrier switched to single-wave poll (wave 0 spins,
//   others released via __syncthreads) to cut LLC poll contention 4x.
//  Decoder: persistent (R10) + critical-path cuts:
//   - af0 (h0) register-carry from phase B into next step's phase A
//     (Whh0 stream GEMM starts immediately at barrier release).
//   - single-wave poll barriers.
//   - out[t-1] written from the inp values already loaded (no extra predbuf read).
//   - cell state in registers; Wih1+Whh1 in LDS (128KB); Whh0 streamed from L2.
//   pred stays fp32 via atomicAdd into predbuf (accuracy).

typedef short short8v __attribute__((ext_vector_type(8)));
typedef float float4v __attribute__((ext_vector_type(4)));
typedef unsigned long long u64;
#define MFMA(a,b,c) __builtin_amdgcn_mfma_f32_16x16x32_bf16((a),(b),(c),0,0,0)

#define HIDN 256
#define TLEN 512
#define HPE  ((size_t)256 * HIDN)     // enc h slot elements (128 KB)
#define HPD  ((size_t)4096 * HIDN)    // dec h slot elements (2 MB bf16)

__device__ __forceinline__ unsigned short f2b(float f) {
    unsigned int u = __float_as_uint(f);
    unsigned int r = ((u >> 16) & 1u) + 0x7FFFu;
    return (unsigned short)((u + r) >> 16);
}
__device__ __forceinline__ float sigf(float x) { return 1.0f / (1.0f + __expf(-x)); }
__device__ __forceinline__ float tanhf2(float x) { return 1.0f - 2.0f / (1.0f + __expf(2.0f * x)); }

__device__ __forceinline__ void hpair_store(unsigned short* buf, int row, int hid,
                                            float h, int lane) {
    unsigned int mine = f2b(h);
    unsigned int part = (unsigned int)__shfl_xor((int)mine, 1);
    if (!(lane & 1)) {
        __hip_atomic_store((unsigned int*)&buf[(size_t)row * HIDN + hid],
                           mine | (part << 16),
                           __ATOMIC_RELAXED, __HIP_MEMORY_SCOPE_AGENT);
    }
}

// agent-scope (LLC-coherent) 16B A-frag load as 2x u64
__device__ __forceinline__ short8v ldA16(const unsigned short* p) {
    union { u64 d[2]; short8v v; } w;
    w.d[0] = __hip_atomic_load((const u64*)p,     __ATOMIC_RELAXED, __HIP_MEMORY_SCOPE_AGENT);
    w.d[1] = __hip_atomic_load((const u64*)p + 1, __ATOMIC_RELAXED, __HIP_MEMORY_SCOPE_AGENT);
    return w.v;
}

// single-wave poll barrier: wave 0 spins on nfl flags, everyone else parked at
// the release __syncthreads. 4x less LLC poll traffic than all-wave spin.
__device__ __forceinline__ void bar_sync(unsigned int* fl, int slot, unsigned int target,
                                         int nfl, int lane, int tid, int& dead) {
    __syncthreads();   // drains vmcnt -> h stores committed before flag store
    if (tid == 0)
        __hip_atomic_store(&fl[slot], target, __ATOMIC_RELAXED, __HIP_MEMORY_SCOPE_AGENT);
    if (tid < 64 && !dead) {
        int guard = 0;
        for (;;) {
            unsigned int v = 0xFFFFFFFFu;
            if (lane < nfl)
                v = __hip_atomic_load(&fl[lane], __ATOMIC_RELAXED, __HIP_MEMORY_SCOPE_AGENT);
            if (__ballot(v >= target) == ~0ull) break;
            if (++guard > (1 << 20)) { dead = 1; break; }
        }
    }
    __syncthreads();   // release waves 1..3
    __builtin_amdgcn_fence(__ATOMIC_ACQUIRE, "workgroup");
}

// ==================== DEC WEIGHT PACK (one-time) ====================
// pk slot = ((mat*64 + n)*8 + kc)*64 + lane; element W[n*16+(lane&15)][kc*32+(lane>>4)*8+i]
__global__ __launch_bounds__(256) void pack_kernel(
    const float* __restrict__ Whh0, const float* __restrict__ Wih1,
    const float* __restrict__ Whh1, unsigned short* __restrict__ pk)
{
    int gid = blockIdx.x * 256 + threadIdx.x;   // 0..98303
    int lane = gid & 63;
    int kc = (gid >> 6) & 7;
    int n  = (gid >> 9) & 63;
    int mat = gid >> 15;
    const float* W = (mat == 0) ? Whh0 : ((mat == 1) ? Wih1 : Whh1);
    const float* p = W + (size_t)(n * 16 + (lane & 15)) * HIDN
                       + (kc << 5) + ((lane >> 4) << 3);
    short8v v;
#pragma unroll
    for (int i = 0; i < 8; ++i) v[i] = (short)f2b(p[i]);
    *(short8v*)&pk[(size_t)gid << 3] = v;
}

// ============================ ENCODER ============================
__global__ __launch_bounds__(256, 1) void enc_kernel(
    const float* __restrict__ x,
    const float* __restrict__ Wih0, const float* __restrict__ Whh0, const float* __restrict__ b0,
    const float* __restrict__ Wih1, const float* __restrict__ Whh1, const float* __restrict__ b1,
    unsigned short* __restrict__ h0e, unsigned short* __restrict__ h1e,
    unsigned short* __restrict__ finh0, unsigned short* __restrict__ finh1,
    float* __restrict__ finc0, float* __restrict__ finc1,
    unsigned int* __restrict__ flags)
{
    const int tid = threadIdx.x, lane = tid & 63, wv = tid >> 6;
    const int bt = blockIdx.x & 15, hs = blockIdx.x >> 4;
    const int row0 = bt << 4, hidb = hs << 4;
    const int l15 = lane & 15, q = lane >> 4, q8 = q << 3;

    __shared__ float gt[12][16][17];
    __shared__ float xt[16][TLEN + 1];
    __shared__ unsigned short hst0[16][264], hst1[16][264];

    for (int idx = tid; idx < 16 * TLEN; idx += 256) {
        int r = idx >> 9, c = idx & 511;
        xt[r][c] = x[(size_t)(row0 + r) * TLEN + c];
    }

    short8v wf[3][8];
    {
        const float* Ws[3] = {Whh0, Wih1, Whh1};
#pragma unroll
        for (int j = 0; j < 3; ++j) {
            int p = wv * 3 + j;
            int mat = p >> 2, g = p & 3;
            const float* rp = Ws[mat] + (size_t)((g << 8) + hidb + l15) * HIDN + q8;
#pragma unroll
            for (int kc = 0; kc < 8; ++kc) {
                short8v v;
#pragma unroll
                for (int i = 0; i < 8; ++i) v[i] = (short)f2b(rp[(kc << 5) + i]);
                wf[j][kc] = v;
            }
        }
    }

    const int erow = tid >> 4, ehid = tid & 15;
    const int grow = row0 + erow, ghid = hidb + ehid;
    float wx[4], bb0v[4], bb1v[4];
#pragma unroll
    for (int g = 0; g < 4; ++g) {
        wx[g]   = Wih0[(g << 8) + ghid];
        bb0v[g] = b0[(g << 8) + ghid];
        bb1v[g] = b1[(g << 8) + ghid];
    }
    float c0 = 0.f, c1 = 0.f;
    unsigned int* fl = flags + (bt << 4);
    int dead = 0;
    const bool useH0 = (wv <= 2), useH1 = (wv >= 2);
    __syncthreads();

    for (int s = 1; s <= 513; ++s) {
        const unsigned short* hr0 = h0e + (size_t)((s - 1) & 1) * HPE;
        const unsigned short* hr1 = h1e + (size_t)((s - 1) & 1) * HPE;
        unsigned short* hw0 = h0e + (size_t)(s & 1) * HPE;
        unsigned short* hw1 = h1e + (size_t)(s & 1) * HPE;

        if (s >= 2) {
#pragma unroll
            for (int k = 0; k < 4; ++k) {
                int oo = tid + (k << 8);
                int r = oo >> 6, cu = oo & 63;
                u64 v = __hip_atomic_load((const u64*)&hr0[(size_t)(row0 + r) * HIDN + (cu << 2)],
                                          __ATOMIC_RELAXED, __HIP_MEMORY_SCOPE_AGENT);
                *(u64*)&hst0[r][cu << 2] = v;
            }
        }
        if (s >= 3) {
#pragma unroll
            for (int k = 0; k < 4; ++k) {
                int oo = tid + (k << 8);
                int r = oo >> 6, cu = oo & 63;
                u64 v = __hip_atomic_load((const u64*)&hr1[(size_t)(row0 + r) * HIDN + (cu << 2)],
                                          __ATOMIC_RELAXED, __HIP_MEMORY_SCOPE_AGENT);
                *(u64*)&hst1[r][cu << 2] = v;
            }
        }
        __syncthreads();

        float4v acc[3] = {{0,0,0,0},{0,0,0,0},{0,0,0,0}};
        short8v a0f[8], a1f[8];
        if (useH0 && s >= 2) {
#pragma unroll
            for (int kc = 0; kc < 8; ++kc) a0f[kc] = *(const short8v*)&hst0[l15][(kc << 5) + q8];
        }
        if (useH1 && s >= 3) {
#pragma unroll
            for (int kc = 0; kc < 8; ++kc) a1f[kc] = *(const short8v*)&hst1[l15][(kc << 5) + q8];
        }
#pragma unroll
        for (int j = 0; j < 3; ++j) {
            int p = wv * 3 + j;
            int mat = p >> 2;
            bool active = (mat == 0) ? (s >= 2 && s <= 512)
                        : (mat == 1) ? (s >= 2)
                                     : (s >= 3);
            if (active) {
                if (mat == 2) {
#pragma unroll
                    for (int kc = 0; kc < 8; ++kc) acc[j] = MFMA(a1f[kc], wf[j][kc], acc[j]);
                } else {
#pragma unroll
                    for (int kc = 0; kc < 8; ++kc) acc[j] = MFMA(a0f[kc], wf[j][kc], acc[j]);
                }
            }
        }
#pragma unroll
        for (int j = 0; j < 3; ++j) {
            int p = wv * 3 + j;
#pragma unroll
            for (int r = 0; r < 4; ++r) gt[p][(q << 2) + r][l15] = acc[j][r];
        }
        __syncthreads();

        if (s <= 512) {
            float xv = xt[erow][s - 1];
            float gi = gt[0][erow][ehid] + wx[0] * xv + bb0v[0];
            float gf = gt[1][erow][ehid] + wx[1] * xv + bb0v[1];
            float gg = gt[2][erow][ehid] + wx[2] * xv + bb0v[2];
            float go = gt[3][erow][ehid] + wx[3] * xv + bb0v[3];
            c0 = sigf(gf) * c0 + sigf(gi) * tanhf2(gg);
            float h0n = sigf(go) * tanhf2(c0);
            hpair_store(hw0, grow, ghid, h0n, lane);
            if (s == 512) {
                finh0[(size_t)grow * HIDN + ghid] = f2b(h0n);
                finc0[(size_t)grow * HIDN + ghid] = c0;
            }
        }
        if (s >= 2) {
            float gi = gt[4][erow][ehid] + gt[8][erow][ehid]  + bb1v[0];
            float gf = gt[5][erow][ehid] + gt[9][erow][ehid]  + bb1v[1];
            float gg = gt[6][erow][ehid] + gt[10][erow][ehid] + bb1v[2];
            float go = gt[7][erow][ehid] + gt[11][erow][ehid] + bb1v[3];
            c1 = sigf(gf) * c1 + sigf(gi) * tanhf2(gg);
            float h1n = sigf(go) * tanhf2(c1);
            hpair_store(hw1, grow, ghid, h1n, lane);
            if (s == 513) {
                finh1[(size_t)grow * HIDN + ghid] = f2b(h1n);
                finc1[(size_t)grow * HIDN + ghid] = c1;
            }
        }
        bar_sync(fl, hs, (unsigned int)s, 16, lane, tid, dead);
    }
}

// ===================== PERSISTENT DECODER =====================
// 256 blocks = 32 row-groups(128 rows) x 8 hid-slices(32 hid), 1 block/CU.
__global__ __launch_bounds__(256, 1) void dec_kernel(
    const unsigned short* __restrict__ pk,
    const float* __restrict__ Wih0, const float* __restrict__ b0,
    const float* __restrict__ b1, const float* __restrict__ outW,
    const float* __restrict__ outb, const float* __restrict__ dinit,
    const unsigned short* __restrict__ finh0, const float* __restrict__ finc0,
    const unsigned short* __restrict__ finh1, const float* __restrict__ finc1,
    unsigned short* __restrict__ h0d, unsigned short* __restrict__ h1d,
    float* __restrict__ predbuf, unsigned int* __restrict__ flags,
    float* __restrict__ out)
{
    extern __shared__ unsigned short wlds[];   // 128KB: [mt(2)][nf(8)][kc(8)][ln(64)] x16B
    const int tid = threadIdx.x, lane = tid & 63, wv = tid >> 6;
    const int rg = blockIdx.x & 31, hsl = blockIdx.x >> 5;
    const int row0 = rg << 7, hidb = hsl << 5;
    const int l15 = lane & 15, q = lane >> 4, q8 = q << 3;

    // stage Wih1 (mt=0) + Whh1 (mt=1) B-frags into LDS, once
#pragma unroll
    for (int k = 0; k < 32; ++k) {
        int sl = tid + (k << 8);
        int ln = sl & 63, kc = (sl >> 6) & 7, nf = (sl >> 9) & 7, mt = sl >> 12;
        int n = ((mt + 1) << 6) + ((nf >> 1) << 4) + (hsl << 1) + (nf & 1);
        *(short8v*)&wlds[sl << 3] =
            *(const short8v*)&pk[((size_t)((n << 3) + kc) << 9) + (ln << 3)];
    }

    const float outb_v = outb[0];
    float wx2[2][4], bb0v[2][4], bb1v[2][4], ow2[2];
#pragma unroll
    for (int u = 0; u < 2; ++u) {
        int hid = hidb + (u << 4) + l15;
        ow2[u] = outW[hid];
#pragma unroll
        for (int g = 0; g < 4; ++g) {
            wx2[u][g]  = Wih0[(g << 8) + hid];
            bb0v[u][g] = b0[(g << 8) + hid];
            bb1v[u][g] = b1[(g << 8) + hid];
        }
    }
    // cell state in registers
    float c0r[2][2][4], c1r[2][2][4];
#pragma unroll
    for (int m = 0; m < 2; ++m)
#pragma unroll
        for (int u = 0; u < 2; ++u) {
            int hid = hidb + (u << 4) + l15;
#pragma unroll
            for (int r = 0; r < 4; ++r) {
                int row = row0 + (wv << 5) + (m << 4) + (q << 2) + r;
                c0r[m][u][r] = finc0[(size_t)(row & 255) * HIDN + hid];
                c1r[m][u][r] = finc1[(size_t)(row & 255) * HIDN + hid];
            }
        }

    // af0 register-carry: preload h0(final enc) for t=0
    short8v af0[2][8];
#pragma unroll
    for (int m = 0; m < 2; ++m) {
        int row = (row0 + (wv << 5) + (m << 4) + l15) & 255;
        const unsigned short* p = finh0 + (size_t)row * HIDN + q8;
#pragma unroll
        for (int kc = 0; kc < 8; ++kc) af0[m][kc] = *(const short8v*)&p[kc << 5];
    }

    unsigned int* fl = flags + (rg << 4);
    int dead = 0;
    __syncthreads();

    for (int t = 0; t < 64; ++t) {
        const unsigned short* h1prev = (t == 0) ? finh1 : h1d + (size_t)((t + 1) & 1) * HPD;
        unsigned short* h0w = h0d + (size_t)(t & 1) * HPD;
        unsigned short* h1w = h1d + (size_t)(t & 1) * HPD;
        const int rmask = (t == 0) ? 255 : 0x7FFFFFFF;

        // ---- phase A ----
        // issue af1 (h1(t-1)) loads first (LLC latency hides under Whh0 GEMM)
        short8v af1[2][8];
#pragma unroll
        for (int m = 0; m < 2; ++m) {
            int row = (row0 + (wv << 5) + (m << 4) + l15) & rmask;
            const unsigned short* p1 = h1prev + (size_t)row * HIDN + q8;
#pragma unroll
            for (int kc = 0; kc < 8; ++kc) af1[m][kc] = ldA16(p1 + (kc << 5));
        }
        // input scalar (pred(t-1)+outb or dec_init)
        float inp[2][4];
#pragma unroll
        for (int m = 0; m < 2; ++m)
#pragma unroll
            for (int r = 0; r < 4; ++r) {
                int row = row0 + (wv << 5) + (m << 4) + (q << 2) + r;
                inp[m][r] = (t == 0) ? dinit[row]
                    : __hip_atomic_load(&predbuf[(size_t)(t - 1) * 4096 + row],
                                        __ATOMIC_RELAXED, __HIP_MEMORY_SCOPE_AGENT) + outb_v;
            }
        // out[t-1] from inp (one writer per row: hsl==0, l15==0)
        if (hsl == 0 && t > 0 && l15 == 0) {
#pragma unroll
            for (int m = 0; m < 2; ++m)
#pragma unroll
                for (int r = 0; r < 4; ++r) {
                    int row = row0 + (wv << 5) + (m << 4) + (q << 2) + r;
                    out[(size_t)(((row & 255) << 4) + (row >> 8)) * 64 + (t - 1)] = inp[m][r];
                }
        }

        // acc0 = h0(t-1) @ Whh0 (af0 already in regs; B streamed from L2 pk)
        float4v acc0[2][8];
#pragma unroll
        for (int m = 0; m < 2; ++m)
#pragma unroll
            for (int nf = 0; nf < 8; ++nf) acc0[m][nf] = (float4v){0, 0, 0, 0};
#pragma unroll
        for (int kc = 0; kc < 8; ++kc)
#pragma unroll
            for (int nf = 0; nf < 8; ++nf) {
                int n = ((nf >> 1) << 4) + (hsl << 1) + (nf & 1);
                short8v bf = *(const short8v*)&pk[((size_t)((n << 3) + kc) << 9) + (lane << 3)];
                acc0[0][nf] = MFMA(af0[0][kc], bf, acc0[0][nf]);
                acc0[1][nf] = MFMA(af0[1][kc], bf, acc0[1][nf]);
            }
        // acc1 partial = h1(t-1) @ Whh1 (LDS mt=1)
        float4v acc1[2][8];
#pragma unroll
        for (int m = 0; m < 2; ++m)
#pragma unroll
            for (int nf = 0; nf < 8; ++nf) acc1[m][nf] = (float4v){0, 0, 0, 0};
#pragma unroll
        for (int kc = 0; kc < 8; ++kc)
#pragma unroll
            for (int nf = 0; nf < 8; ++nf) {
                short8v bf = *(const short8v*)&wlds[(size_t)(4096 + (((nf << 3) + kc) << 6) + lane) << 3];
                acc1[0][nf] = MFMA(af1[0][kc], bf, acc1[0][nf]);
                acc1[1][nf] = MFMA(af1[1][kc], bf, acc1[1][nf]);
            }
        // cell0 -> publish h0(t) slice
#pragma unroll
        for (int m = 0; m < 2; ++m)
#pragma unroll
            for (int u = 0; u < 2; ++u) {
                int hid = hidb + (u << 4) + l15;
#pragma unroll
                for (int r = 0; r < 4; ++r) {
                    int row = row0 + (wv << 5) + (m << 4) + (q << 2) + r;
                    float gi = acc0[m][0 + u][r] + wx2[u][0] * inp[m][r] + bb0v[u][0];
                    float gf = acc0[m][2 + u][r] + wx2[u][1] * inp[m][r] + bb0v[u][1];
                    float gg = acc0[m][4 + u][r] + wx2[u][2] * inp[m][r] + bb0v[u][2];
                    float go = acc0[m][6 + u][r] + wx2[u][3] * inp[m][r] + bb0v[u][3];
                    float cn = sigf(gf) * c0r[m][u][r] + sigf(gi) * tanhf2(gg);
                    c0r[m][u][r] = cn;
                    float h0n = sigf(go) * tanhf2(cn);
                    hpair_store(h0w, row, hid, h0n, lane);
                }
            }
        bar_sync(fl, hsl, (unsigned int)(2 * t + 1), 8, lane, tid, dead);

        // ---- phase B: load h0(t) (kept as af0 for next step), Wih1 GEMM ----
#pragma unroll
        for (int m = 0; m < 2; ++m) {
            int row = row0 + (wv << 5) + (m << 4) + l15;
            const unsigned short* p0 = h0w + (size_t)row * HIDN + q8;
#pragma unroll
            for (int kc = 0; kc < 8; ++kc) af0[m][kc] = ldA16(p0 + (kc << 5));
        }
#pragma unroll
        for (int kc = 0; kc < 8; ++kc)
#pragma unroll
            for (int nf = 0; nf < 8; ++nf) {
                short8v bf = *(const short8v*)&wlds[(size_t)((((nf << 3) + kc) << 6) + lane) << 3];
                acc1[0][nf] = MFMA(af0[0][kc], bf, acc1[0][nf]);
                acc1[1][nf] = MFMA(af0[1][kc], bf, acc1[1][nf]);
            }
        // cell1 -> publish h1(t) slice + pred partial (fp32)
        float pp[2][4] = {{0,0,0,0},{0,0,0,0}};
#pragma unroll
        for (int m = 0; m < 2; ++m)
#pragma unroll
            for (int u = 0; u < 2; ++u) {
                int hid = hidb + (u << 4) + l15;
#pragma unroll
                for (int r = 0; r < 4; ++r) {
                    int row = row0 + (wv << 5) + (m << 4) + (q << 2) + r;
                    float gi = acc1[m][0 + u][r] + bb1v[u][0];
                    float gf = acc1[m][2 + u][r] + bb1v[u][1];
                    float gg = acc1[m][4 + u][r] + bb1v[u][2];
                    float go = acc1[m][6 + u][r] + bb1v[u][3];
                    float cn = sigf(gf) * c1r[m][u][r] + sigf(gi) * tanhf2(gg);
                    c1r[m][u][r] = cn;
                    float h1n = sigf(go) * tanhf2(cn);
                    pp[m][r] += h1n * ow2[u];
                    hpair_store(h1w, row, hid, h1n, lane);
                }
            }
#pragma unroll
        for (int off = 1; off < 16; off <<= 1)
#pragma unroll
            for (int m = 0; m < 2; ++m)
#pragma unroll
                for (int r = 0; r < 4; ++r) pp[m][r] += __shfl_xor(pp[m][r], off);
        if (l15 == 0) {
#pragma unroll
            for (int m = 0; m < 2; ++m)
#pragma unroll
                for (int r = 0; r < 4; ++r) {
                    int row = row0 + (wv << 5) + (m << 4) + (q << 2) + r;
                    atomicAdd(&predbuf[(size_t)t * 4096 + row], pp[m][r]);
                }
        }
        bar_sync(fl, hsl, (unsigned int)(2 * t + 2), 8, lane, tid, dead);
    }

    // final output column t=63
    if (hsl == 0 && tid < 128) {
        int row = row0 + tid;
        float v = __hip_atomic_load(&predbuf[(size_t)63 * 4096 + row],
                                    __ATOMIC_RELAXED, __HIP_MEMORY_SCOPE_AGENT) + outb_v;
        out[(size_t)(((row & 255) << 4) + (row >> 8)) * 64 + 63] = v;
    }
}

extern "C" void kernel_launch(void* const* d_in, const int* in_sizes, int n_in,
                              void* d_out, int out_size, void* d_ws, size_t ws_size,
                              hipStream_t stream) {
    (void)in_sizes; (void)n_in; (void)out_size; (void)ws_size;
    const float* x     = (const float*)d_in[0];
    const float* eWih0 = (const float*)d_in[1];
    const float* eWhh0 = (const float*)d_in[2];
    const float* eb0   = (const float*)d_in[3];
    const float* eWih1 = (const float*)d_in[4];
    const float* eWhh1 = (const float*)d_in[5];
    const float* eb1   = (const float*)d_in[6];
    const float* dWih0 = (const float*)d_in[7];
    const float* dWhh0 = (const float*)d_in[8];
    const float* db0   = (const float*)d_in[9];
    const float* dWih1 = (const float*)d_in[10];
    const float* dWhh1 = (const float*)d_in[11];
    const float* db1   = (const float*)d_in[12];
    const float* outW  = (const float*)d_in[13];
    const float* outb  = (const float*)d_in[14];
    const float* dinit = (const float*)d_in[15];

    char* ws = (char*)d_ws;
    unsigned short* h0e   = (unsigned short*)(ws);               // 256 KB
    unsigned short* h1e   = (unsigned short*)(ws + 262144);      // 256 KB
    unsigned short* finh0 = (unsigned short*)(ws + 524288);      // 128 KB
    unsigned short* finh1 = (unsigned short*)(ws + 655360);      // 128 KB
    float* finc0          = (float*)(ws + 786432);               // 256 KB
    float* finc1          = (float*)(ws + 1048576);              // 256 KB
    unsigned int* fle     = (unsigned int*)(ws + 1310720);       // 1 KB
    unsigned short* pk    = (unsigned short*)(ws + 1311744);     // 1.5 MB
    unsigned short* h0d   = (unsigned short*)(ws + 2884608);     // 2x2 MB
    unsigned short* h1d   = (unsigned short*)(ws + 7078912);     // 2x2 MB
    unsigned int* fld     = (unsigned int*)(ws + 11273216);      // 2 KB (32 rg x 16)
    float* predraw        = (float*)(ws + 19661824);             // 1 MB (64 x 4096)

    hipMemsetAsync(fle, 0, 1024, stream);
    hipMemsetAsync(fld, 0, 2048, stream);
    hipMemsetAsync(predraw, 0, 64 * 4096 * 4, stream);
    hipFuncSetAttribute((const void*)dec_kernel,
                        hipFuncAttributeMaxDynamicSharedMemorySize, 131072);

    pack_kernel<<<384, 256, 0, stream>>>(dWhh0, dWih1, dWhh1, pk);
    enc_kernel<<<256, 256, 0, stream>>>(x, eWih0, eWhh0, eb0, eWih1, eWhh1, eb1,
                                        h0e, h1e, finh0, finh1, finc0, finc1, fle);
    dec_kernel<<<256, 256, 131072, stream>>>(pk, dWih0, db0, db1, outW, outb, dinit,
                                             finh0, finc0, finh1, finc1,
                                             h0d, h1d, predraw, fld, (float*)d_out);
}